// Round 11
// baseline (72.305 us; speedup 1.0000x reference)
//
#include <hip/hip_runtime.h>
#include <stdint.h>

typedef _Float16 f16x8 __attribute__((ext_vector_type(8)));
typedef float f32x4 __attribute__((ext_vector_type(4)));

__device__ __forceinline__ f32x4 MF(f16x8 a, f16x8 b, f32x4 c) {
    return __builtin_amdgcn_mfma_f32_16x16x32_f16(a, b, c, 0, 0, 0);
}
__device__ __forceinline__ uint16_t h16(float v) {
    _Float16 h = (_Float16)v; return __builtin_bit_cast(uint16_t, h);
}
__device__ __forceinline__ uint16_t key16(float v) {
    _Float16 h = (_Float16)fmaxf(v, 0.0f); return __builtin_bit_cast(uint16_t, h);
}
__device__ __forceinline__ uint32_t pack2(float a, float b) {
    return (uint32_t)h16(a) | ((uint32_t)h16(b) << 16);
}

#if defined(__has_builtin)
# if __has_builtin(__builtin_amdgcn_global_load_lds)
#  define HAVE_GLDS 1
# endif
#endif
#ifndef HAVE_GLDS
# define HAVE_GLDS 0
#endif

// ======== Kernel A: X[n][c][t][f] f32 -> W[n][f][c][t] f16 (u32 t-pairs) ====
// Full 64B lines on BOTH sides. LDS transpose, XOR-swizzled banks.
__global__ __launch_bounds__(256, 4)
void gfc_prep(const float* __restrict__ X, uint32_t* __restrict__ W) {
    __shared__ uint32_t Tp[128][64];   // [t-pair][f], col = f ^ (4*((p>>2)&7))
    int n = blockIdx.x >> 6, c = blockIdx.x & 63;
    int tid = threadIdx.x;
    const float* src = X + ((size_t)n * 64 + c) * 16384;

    // phase 1: coalesced reads; pair t/t+1 via shfl_xor(16); pack f16; LDS
    bool active = ((tid >> 4) & 1) == 0;
    int f0 = 4 * (tid & 15);
    #pragma unroll
    for (int half = 0; half < 2; ++half) {
        float4 v[8];
        #pragma unroll
        for (int i = 0; i < 8; ++i)
            v[i] = *(const float4*)(src + (size_t)(half * 8 + i) * 1024 + tid * 4);
        #pragma unroll
        for (int i = 0; i < 8; ++i) {
            float4 pv;
            pv.x = __shfl_xor(v[i].x, 16, 64);
            pv.y = __shfl_xor(v[i].y, 16, 64);
            pv.z = __shfl_xor(v[i].z, 16, 64);
            pv.w = __shfl_xor(v[i].w, 16, 64);
            if (active) {
                int p = 8 * (half * 8 + i) + (tid >> 5);   // t-pair row
                int col = f0 ^ (4 * ((p >> 2) & 7));
                uint32_t w0 = pack2(v[i].x, pv.x);
                uint32_t w1 = pack2(v[i].y, pv.y);
                uint32_t w2 = pack2(v[i].z, pv.z);
                uint32_t w3 = pack2(v[i].w, pv.w);
                uint4 q; q.x = w0; q.y = w1; q.z = w2; q.w = w3;
                *(uint4*)&Tp[p][col] = q;
            }
        }
    }
    __syncthreads();

    // phase 2: lane k writes bytes [16k,16k+16) of W row (f, c) -- full lines
    int wv = tid >> 6, l = tid & 63;
    int k = l & 31, fh = l >> 5;
    int sw = 4 * (k & 7);
    #pragma unroll
    for (int e = 0; e < 8; ++e) {
        int f = wv * 16 + 2 * e + fh;
        int col = f ^ sw;                 // (p>>2)&7 == k&7 for p=4k..4k+3
        uint4 q;
        q.x = Tp[4 * k + 0][col];
        q.y = Tp[4 * k + 1][col];
        q.z = Tp[4 * k + 2][col];
        q.w = Tp[4 * k + 3][col];
        uint32_t* dst = W + ((size_t)(n * 64 + f) * 64 + c) * 128 + k * 4;
        *(uint4*)dst = q;
    }
}

// ======== Kernel B: gram from W + median + exp (r9-proven) ========
__global__ __launch_bounds__(512, 2)
void gfc_main2(const uint16_t* __restrict__ W, const float* __restrict__ gp,
               float* __restrict__ out) {
    __shared__ float Rbuf[4][64];
    __shared__ uint32_t EX[8][1024];

    int j = blockIdx.x;
    int xcd = j & 7, r = j >> 3;
    int fq = r & 15, nh = r >> 4;
    int n = xcd * 4 + nh;
    int f0 = fq * 4;

    int tid = threadIdx.x;
    int wid = tid >> 6, lane = tid & 63;
    int w4 = wid & 3, hi = wid >> 2;
    int l4 = lane & 15, lg = lane >> 4;

    float p10 = exp2f(gp[0] * 3.3219280948873623f);
    const uint16_t* Wf = W + ((size_t)n * 64 + f0 + w4) * 16384;

    f32x4 dd[2][4];
    #pragma unroll
    for (int a = 0; a < 2; ++a)
        #pragma unroll
        for (int b = 0; b < 4; ++b) dd[a][b] = f32x4{0, 0, 0, 0};

    #pragma unroll
    for (int ks = 0; ks < 8; ++ks) {
        f16x8 fr[4];
        #pragma unroll
        for (int i2 = 0; i2 < 4; ++i2)
            fr[i2] = *(const f16x8*)(Wf + (i2 * 16 + l4) * 256 + ks * 32 + lg * 8);
        if (!hi) {
            #pragma unroll
            for (int tj = 0; tj < 4; ++tj) {
                dd[0][tj] = MF(fr[tj], fr[0], dd[0][tj]);
                dd[1][tj] = MF(fr[tj], fr[1], dd[1][tj]);
            }
        } else {
            #pragma unroll
            for (int tj = 0; tj < 4; ++tj) {
                dd[0][tj] = MF(fr[tj], fr[2], dd[0][tj]);
                dd[1][tj] = MF(fr[tj], fr[3], dd[1][tj]);
            }
        }
    }

    {
        f32x4 dg0 = hi ? dd[0][2] : dd[0][0];
        f32x4 dg1 = hi ? dd[1][3] : dd[1][1];
        if (lg == (l4 >> 2)) {
            int rr = l4 & 3;
            float v0 = rr == 0 ? dg0[0] : rr == 1 ? dg0[1] : rr == 2 ? dg0[2] : dg0[3];
            float v1 = rr == 0 ? dg1[0] : rr == 1 ? dg1[1] : rr == 2 ? dg1[2] : dg1[3];
            Rbuf[w4][(hi * 2) * 16 + l4] = v0;
            Rbuf[w4][(hi * 2 + 1) * 16 + l4] = v1;
        }
    }
    __syncthreads();

    float Rr0 = Rbuf[w4][(hi * 2) * 16 + l4];
    float Rr1 = Rbuf[w4][(hi * 2 + 1) * 16 + l4];
    #pragma unroll
    for (int tj = 0; tj < 4; ++tj) {
        f32x4 Rc = *(const f32x4*)&Rbuf[w4][tj * 16 + lg * 4];
        #pragma unroll
        for (int rr = 0; rr < 4; ++rr) {
            dd[0][tj][rr] = Rr0 + Rc[rr] - 2.0f * dd[0][tj][rr];
            dd[1][tj][rr] = Rr1 + Rc[rr] - 2.0f * dd[1][tj][rr];
        }
    }

    uint32_t pk[32];
    #pragma unroll
    for (int tt = 0; tt < 2; ++tt) {
        int row = (hi * 2 + tt) * 16 + l4;
        #pragma unroll
        for (int tj = 0; tj < 4; ++tj)
            #pragma unroll
            for (int rp = 0; rp < 2; ++rp) {
                int col0 = tj * 16 + lg * 4 + 2 * rp;
                uint32_t k0 = (row < col0)     ? key16(dd[tt][tj][2 * rp])     : 0x7FFFu;
                uint32_t k1 = (row < col0 + 1) ? key16(dd[tt][tj][2 * rp + 1]) : 0x7FFFu;
                pk[tt * 8 + tj * 2 + rp] = k0 | (k1 << 16);
            }
    }

    {
        uint32_t* mywr = EX[wid];
        #pragma unroll
        for (int e = 0; e < 16; ++e) mywr[e * 64 + lane] = pk[e];
        __syncthreads();
        const uint32_t* prd = EX[wid ^ 4];
        #pragma unroll
        for (int e = 0; e < 16; ++e) pk[16 + e] = prd[e * 64 + lane];
    }

    int u = 0;
    for (int bit = 14; bit >= 0; --bit) {
        uint32_t cand = (uint32_t)(u | (1 << bit));
        int cnt = 0;
        #pragma unroll
        for (int i = 0; i < 32; ++i) {
            cnt += ((pk[i] & 0xFFFFu) < cand) ? 1 : 0;
            cnt += ((pk[i] >> 16) < cand) ? 1 : 0;
        }
        #pragma unroll
        for (int off = 32; off; off >>= 1) cnt += __shfl_xor(cnt, off, 64);
        if (cnt <= 1008) u |= (1 << bit);
    }
    float sigma2 = (float)__builtin_bit_cast(_Float16, (uint16_t)u);
    float ninv = -1.0f / (2.0f * p10 * sigma2);

    float* op = out + ((size_t)(n * 64 + f0 + w4) << 12);
    #pragma unroll
    for (int tt = 0; tt < 2; ++tt) {
        int row = (hi * 2 + tt) * 16 + l4;
        #pragma unroll
        for (int tj = 0; tj < 4; ++tj) {
            float4 rv;
            rv.x = __expf(dd[tt][tj][0] * ninv);
            rv.y = __expf(dd[tt][tj][1] * ninv);
            rv.z = __expf(dd[tt][tj][2] * ninv);
            rv.w = __expf(dd[tt][tj][3] * ninv);
            *(float4*)(op + row * 64 + tj * 16 + lg * 4) = rv;
        }
    }
}

// ======== Fallback: r10 DMA monolith (proven, 67.9us) ========
__global__ __launch_bounds__(512, 2)
void gfc_fb(const float* __restrict__ X, const float* __restrict__ gp,
            float* __restrict__ out) {
    __shared__ __align__(16) unsigned char XS[65536];
    __shared__ float Rbuf[4][64];
    int j = blockIdx.x;
    int xcd = j & 7, s = j >> 3;
    int gi = s >> 2, fq4 = s & 3;
    int g = gi * 8 + xcd;
    int n = g >> 2, f16g = g & 3;
    int f0 = f16g * 16 + fq4 * 4;
    int tid = threadIdx.x;
    int wid = tid >> 6, lane = tid & 63;
    int w4 = wid & 3, hi = wid >> 2;
    int l4 = lane & 15, lg = lane >> 4;
    int pos = lane & 31, cs = lane >> 5;
    float p10 = exp2f(gp[0] * 3.3219280948873623f);
    const unsigned char* Xb = (const unsigned char*)(X + (size_t)n * 1048576 + f0);
    f32x4 dd[2][4];
    #pragma unroll
    for (int a = 0; a < 2; ++a)
        #pragma unroll
        for (int b = 0; b < 4; ++b) dd[a][b] = f32x4{0, 0, 0, 0};
    auto stage = [&](int bsel, int T0) {
        unsigned char* bb = XS + bsel * 32768;
        #pragma unroll
        for (int i = 0; i < 4; ++i) {
            int c0 = wid * 8 + i * 2;
            int c  = c0 + cs;
            int tt = pos ^ (c & 15);
            const unsigned char* gsrc = Xb + (size_t)c * 65536 + (size_t)(T0 + tt) * 256;
#if HAVE_GLDS
            __builtin_amdgcn_global_load_lds(
                (const uint32_t __attribute__((address_space(1)))*)(uintptr_t)gsrc,
                (uint32_t __attribute__((address_space(3)))*)(uintptr_t)(bb + c0 * 512),
                16, 0, 0);
#else
            *(uint4*)(bb + c0 * 512 + lane * 16) = *(const uint4*)gsrc;
#endif
        }
    };
    auto gram = [&](int bsel) {
        const float* B = (const float*)(XS + bsel * 32768);
        f16x8 fr[4];
        #pragma unroll
        for (int i2 = 0; i2 < 4; ++i2) {
            int c = i2 * 16 + l4;
            int base = c * 128 + w4;
            float v[8];
            #pragma unroll
            for (int jj = 0; jj < 8; ++jj) {
                int tl = lg * 8 + jj;
                v[jj] = B[base + (((tl ^ l4)) << 2)];
            }
            f16x8 f;
            #pragma unroll
            for (int jj = 0; jj < 8; ++jj) f[jj] = (_Float16)v[jj];
            fr[i2] = f;
        }
        if (!hi) {
            #pragma unroll
            for (int tj = 0; tj < 4; ++tj) {
                dd[0][tj] = MF(fr[tj], fr[0], dd[0][tj]);
                dd[1][tj] = MF(fr[tj], fr[1], dd[1][tj]);
            }
        } else {
            #pragma unroll
            for (int tj = 0; tj < 4; ++tj) {
                dd[0][tj] = MF(fr[tj], fr[2], dd[0][tj]);
                dd[1][tj] = MF(fr[tj], fr[3], dd[1][tj]);
            }
        }
    };
    stage(0, 0);
    __syncthreads();
    #pragma unroll
    for (int k = 0; k < 8; ++k) {
        if (k < 7) stage((k + 1) & 1, (k + 1) * 32);
        gram(k & 1);
        if (k < 7) __syncthreads();
    }
    {
        f32x4 dg0 = hi ? dd[0][2] : dd[0][0];
        f32x4 dg1 = hi ? dd[1][3] : dd[1][1];
        if (lg == (l4 >> 2)) {
            int rr = l4 & 3;
            float v0 = rr == 0 ? dg0[0] : rr == 1 ? dg0[1] : rr == 2 ? dg0[2] : dg0[3];
            float v1 = rr == 0 ? dg1[0] : rr == 1 ? dg1[1] : rr == 2 ? dg1[2] : dg1[3];
            Rbuf[w4][(hi * 2) * 16 + l4] = v0;
            Rbuf[w4][(hi * 2 + 1) * 16 + l4] = v1;
        }
    }
    __syncthreads();
    float Rr0 = Rbuf[w4][(hi * 2) * 16 + l4];
    float Rr1 = Rbuf[w4][(hi * 2 + 1) * 16 + l4];
    #pragma unroll
    for (int tj = 0; tj < 4; ++tj) {
        f32x4 Rc = *(const f32x4*)&Rbuf[w4][tj * 16 + lg * 4];
        #pragma unroll
        for (int rr = 0; rr < 4; ++rr) {
            dd[0][tj][rr] = Rr0 + Rc[rr] - 2.0f * dd[0][tj][rr];
            dd[1][tj][rr] = Rr1 + Rc[rr] - 2.0f * dd[1][tj][rr];
        }
    }
    uint32_t pk[32];
    #pragma unroll
    for (int tt = 0; tt < 2; ++tt) {
        int row = (hi * 2 + tt) * 16 + l4;
        #pragma unroll
        for (int tj = 0; tj < 4; ++tj)
            #pragma unroll
            for (int rp = 0; rp < 2; ++rp) {
                int col0 = tj * 16 + lg * 4 + 2 * rp;
                uint32_t k0 = (row < col0)     ? key16(dd[tt][tj][2 * rp])     : 0x7FFFu;
                uint32_t k1 = (row < col0 + 1) ? key16(dd[tt][tj][2 * rp + 1]) : 0x7FFFu;
                pk[tt * 8 + tj * 2 + rp] = k0 | (k1 << 16);
            }
    }
    {
        uint32_t* base = (uint32_t*)(XS + w4 * 8192);
        uint32_t* mywr = base + hi * 1024;
        #pragma unroll
        for (int e = 0; e < 16; ++e) mywr[e * 64 + lane] = pk[e];
        __syncthreads();
        const uint32_t* prd = base + (hi ^ 1) * 1024;
        #pragma unroll
        for (int e = 0; e < 16; ++e) pk[16 + e] = prd[e * 64 + lane];
    }
    int u = 0;
    for (int bit = 14; bit >= 0; --bit) {
        uint32_t cand = (uint32_t)(u | (1 << bit));
        int cnt = 0;
        #pragma unroll
        for (int i = 0; i < 32; ++i) {
            cnt += ((pk[i] & 0xFFFFu) < cand) ? 1 : 0;
            cnt += ((pk[i] >> 16) < cand) ? 1 : 0;
        }
        #pragma unroll
        for (int off = 32; off; off >>= 1) cnt += __shfl_xor(cnt, off, 64);
        if (cnt <= 1008) u |= (1 << bit);
    }
    float sigma2 = (float)__builtin_bit_cast(_Float16, (uint16_t)u);
    float ninv = -1.0f / (2.0f * p10 * sigma2);
    float* op = out + ((size_t)(n * 64 + f0 + w4) << 12);
    #pragma unroll
    for (int tt = 0; tt < 2; ++tt) {
        int row = (hi * 2 + tt) * 16 + l4;
        #pragma unroll
        for (int tj = 0; tj < 4; ++tj) {
            float4 rv;
            rv.x = __expf(dd[tt][tj][0] * ninv);
            rv.y = __expf(dd[tt][tj][1] * ninv);
            rv.z = __expf(dd[tt][tj][2] * ninv);
            rv.w = __expf(dd[tt][tj][3] * ninv);
            *(float4*)(op + row * 64 + tj * 16 + lg * 4) = rv;
        }
    }
}

extern "C" void kernel_launch(void* const* d_in, const int* in_sizes, int n_in,
                              void* d_out, int out_size, void* d_ws, size_t ws_size,
                              hipStream_t stream) {
    (void)in_sizes; (void)n_in; (void)out_size;
    const float* X  = (const float*)d_in[0];
    const float* gp = (const float*)d_in[1];
    float* outp = (float*)d_out;
    if (ws_size >= (size_t)67108864) {
        gfc_prep<<<2048, 256, 0, stream>>>(X, (uint32_t*)d_ws);
        gfc_main2<<<512, 512, 0, stream>>>((const uint16_t*)d_ws, gp, outp);
    } else {
        gfc_fb<<<512, 512, 0, stream>>>(X, gp, outp);
    }
}

// Round 12
// 69.257 us; speedup vs baseline: 1.0440x; 1.0440x over previous
//
#include <hip/hip_runtime.h>
#include <stdint.h>

typedef _Float16 f16x8 __attribute__((ext_vector_type(8)));
typedef float f32x4 __attribute__((ext_vector_type(4)));

__device__ __forceinline__ uint16_t h16(float v) {
    _Float16 h = (_Float16)v; return __builtin_bit_cast(uint16_t, h);
}
__device__ __forceinline__ uint16_t key16(float v) {
    _Float16 h = (_Float16)fmaxf(v, 0.0f); return __builtin_bit_cast(uint16_t, h);
}
__device__ __forceinline__ uint32_t pack2(float a, float b) {
    return (uint32_t)h16(a) | ((uint32_t)h16(b) << 16);
}
__device__ __forceinline__ f32x4 MF(f16x8 a, f16x8 b, f32x4 c) {
    return __builtin_amdgcn_mfma_f32_16x16x32_f16(a, b, c, 0, 0, 0);
}

// 4 blocks/CU: LDS ~34 KB, VGPR <= 64. Single 32 KB stage buffer
// (4 f-slices x 64 c-rows x 128 B = 64 t f16), granule-XOR swizzle:
// granule(16B = 8t) index g ^= (c & 7); b128 frag reads conflict-minimal,
// within-granule t-order untouched (A/B k-pairing consistent).
__global__ __launch_bounds__(512, 4)
void gfc_main(const float* __restrict__ X, const float* __restrict__ gp,
              float* __restrict__ out) {
    __shared__ __align__(16) unsigned char XS[32768];   // stage; reused for exch
    __shared__ float Rbuf[4][64];

    // XCD swizzle: 4 sibling f-quads of one (n, 16-f line group) share an XCD
    int j = blockIdx.x;
    int xcd = j & 7, s = j >> 3;
    int gi = s >> 2, fq4 = s & 3;
    int g = gi * 8 + xcd;
    int n = g >> 2, f16g = g & 3;
    int f0 = f16g * 16 + fq4 * 4;

    int tid = threadIdx.x;
    int wid = tid >> 6, lane = tid & 63;
    int w4 = wid & 3, hi = wid >> 2;     // f within quad; row-half of C
    int l4 = lane & 15, lg = lane >> 4;

    float p10 = exp2f(gp[0] * 3.3219280948873623f);   // 10^gammad
    const float* Xn = X + (size_t)n * 1048576 + f0;

    f32x4 dd[2][4];
    #pragma unroll
    for (int a = 0; a < 2; ++a)
        #pragma unroll
        for (int b = 0; b < 4; ++b) dd[a][b] = f32x4{0, 0, 0, 0};

    // ---- 4 chunks of 64 t, single buffer, serial within block ----
    for (int ch = 0; ch < 4; ++ch) {
        float4 va[4], vb[4];
        #pragma unroll
        for (int it = 0; it < 4; ++it) {           // 8 loads in flight
            int item = it * 512 + tid;
            int c = item >> 5, tp = item & 31;
            const float* p = Xn + ((size_t)c * 256 + ch * 64 + 2 * tp) * 64;
            va[it] = *(const float4*)p;            // t = ch*64 + 2tp
            vb[it] = *(const float4*)(p + 64);     // t = ch*64 + 2tp + 1
        }
        #pragma unroll
        for (int it = 0; it < 4; ++it) {
            int item = it * 512 + tid;
            int c = item >> 5, tp = item & 31;
            int o = c * 128 + ((tp * 4) ^ ((c & 7) << 4));
            *(uint32_t*)(XS + o)         = pack2(va[it].x, vb[it].x);
            *(uint32_t*)(XS +  8192 + o) = pack2(va[it].y, vb[it].y);
            *(uint32_t*)(XS + 16384 + o) = pack2(va[it].z, vb[it].z);
            *(uint32_t*)(XS + 24576 + o) = pack2(va[it].w, vb[it].w);
        }
        __syncthreads();   // stage visible

        const unsigned char* bp = XS + w4 * 8192;
        #pragma unroll
        for (int ks = 0; ks < 2; ++ks) {
            f16x8 fr[4];
            #pragma unroll
            for (int i2 = 0; i2 < 4; ++i2)
                fr[i2] = *(const f16x8*)(bp + (i2 * 16 + l4) * 128 +
                                         ((ks * 64 + lg * 16) ^ ((l4 & 7) << 4)));
            if (!hi) {
                #pragma unroll
                for (int tj = 0; tj < 4; ++tj) {
                    dd[0][tj] = MF(fr[tj], fr[0], dd[0][tj]);
                    dd[1][tj] = MF(fr[tj], fr[1], dd[1][tj]);
                }
            } else {
                #pragma unroll
                for (int tj = 0; tj < 4; ++tj) {
                    dd[0][tj] = MF(fr[tj], fr[2], dd[0][tj]);
                    dd[1][tj] = MF(fr[tj], fr[3], dd[1][tj]);
                }
            }
        }
        __syncthreads();   // gram reads done; buffer reusable
    }

    // ---- R = diag(G). Diag tiles: dd[0][2hi], dd[1][2hi+1]; lg*4+reg==l4 ----
    {
        f32x4 dg0 = hi ? dd[0][2] : dd[0][0];
        f32x4 dg1 = hi ? dd[1][3] : dd[1][1];
        if (lg == (l4 >> 2)) {
            int r = l4 & 3;
            float v0 = r == 0 ? dg0[0] : r == 1 ? dg0[1] : r == 2 ? dg0[2] : dg0[3];
            float v1 = r == 0 ? dg1[0] : r == 1 ? dg1[1] : r == 2 ? dg1[2] : dg1[3];
            Rbuf[w4][(hi * 2) * 16 + l4] = v0;
            Rbuf[w4][(hi * 2 + 1) * 16 + l4] = v1;
        }
    }
    __syncthreads();   // Rbuf ready

    // ---- D = R_row + R_col - 2G in place; 32 keys packed into 16 u32 ----
    float Rr0 = Rbuf[w4][(hi * 2) * 16 + l4];
    float Rr1 = Rbuf[w4][(hi * 2 + 1) * 16 + l4];
    #pragma unroll
    for (int tj = 0; tj < 4; ++tj) {
        f32x4 Rc = *(const f32x4*)&Rbuf[w4][tj * 16 + lg * 4];
        #pragma unroll
        for (int r = 0; r < 4; ++r) {
            dd[0][tj][r] = Rr0 + Rc[r] - 2.0f * dd[0][tj][r];
            dd[1][tj][r] = Rr1 + Rc[r] - 2.0f * dd[1][tj][r];
        }
    }

    uint32_t pk[32];   // [0:16) mine, [16:32) partner's
    #pragma unroll
    for (int tt = 0; tt < 2; ++tt) {
        int row = (hi * 2 + tt) * 16 + l4;
        #pragma unroll
        for (int tj = 0; tj < 4; ++tj)
            #pragma unroll
            for (int rp = 0; rp < 2; ++rp) {
                int col0 = tj * 16 + lg * 4 + 2 * rp;
                uint32_t k0 = (row < col0)     ? key16(dd[tt][tj][2 * rp])     : 0x7FFFu;
                uint32_t k1 = (row < col0 + 1) ? key16(dd[tt][tj][2 * rp + 1]) : 0x7FFFu;
                pk[tt * 8 + tj * 2 + rp] = k0 | (k1 << 16);
            }
    }

    // ---- one-shot packed-key exchange (wid <-> wid^4) through XS ----
    {
        uint32_t* mywr = (uint32_t*)(XS + wid * 4096);
        #pragma unroll
        for (int e = 0; e < 16; ++e) mywr[e * 64 + lane] = pk[e];
        __syncthreads();
        const uint32_t* prd = (const uint32_t*)(XS + (wid ^ 4) * 4096);
        #pragma unroll
        for (int e = 0; e < 16; ++e) pk[16 + e] = prd[e * 64 + lane];
    }

    // ---- exact rank-1008 select on 15-bit f16 keys (redundant per wave) ----
    int u = 0;
    for (int bit = 14; bit >= 0; --bit) {
        uint32_t cand = (uint32_t)(u | (1 << bit));
        int cnt = 0;
        #pragma unroll
        for (int i = 0; i < 32; ++i) {
            cnt += ((pk[i] & 0xFFFFu) < cand) ? 1 : 0;
            cnt += ((pk[i] >> 16) < cand) ? 1 : 0;
        }
        #pragma unroll
        for (int off = 32; off; off >>= 1) cnt += __shfl_xor(cnt, off, 64);
        if (cnt <= 1008) u |= (1 << bit);
    }
    float sigma2 = (float)__builtin_bit_cast(_Float16, (uint16_t)u);
    float ninv = -1.0f / (2.0f * p10 * sigma2);

    // ---- epilogue: A = exp(-D/denom); float4 stores (4 consecutive cols) ----
    float* op = out + ((size_t)(n * 64 + f0 + w4) << 12);
    #pragma unroll
    for (int tt = 0; tt < 2; ++tt) {
        int row = (hi * 2 + tt) * 16 + l4;
        #pragma unroll
        for (int tj = 0; tj < 4; ++tj) {
            float4 rv;
            rv.x = __expf(dd[tt][tj][0] * ninv);
            rv.y = __expf(dd[tt][tj][1] * ninv);
            rv.z = __expf(dd[tt][tj][2] * ninv);
            rv.w = __expf(dd[tt][tj][3] * ninv);
            *(float4*)(op + row * 64 + tj * 16 + lg * 4) = rv;
        }
    }
}

extern "C" void kernel_launch(void* const* d_in, const int* in_sizes, int n_in,
                              void* d_out, int out_size, void* d_ws, size_t ws_size,
                              hipStream_t stream) {
    (void)in_sizes; (void)n_in; (void)out_size; (void)d_ws; (void)ws_size;
    const float* X  = (const float*)d_in[0];
    const float* gp = (const float*)d_in[1];
    float* out = (float*)d_out;
    gfc_main<<<512, 512, 0, stream>>>(X, gp, out);
}